// Round 5
// baseline (328.969 us; speedup 1.0000x reference)
//
#include <hip/hip_runtime.h>
#include <hip/hip_bf16.h>

#define B_ 32
#define K_ 4
#define N_ 512
#define F_ 128

typedef __attribute__((ext_vector_type(8))) short short8;
typedef __attribute__((ext_vector_type(4))) float float4v;

__device__ __forceinline__ unsigned short f2bf(float x) {
    unsigned int u = __builtin_bit_cast(unsigned int, x);
    u += 0x7FFFu + ((u >> 16) & 1u);
    return (unsigned short)(u >> 16);
}

__device__ __forceinline__ short8 pack8(float4v a, float4v b) {
    short8 r;
    r[0] = (short)f2bf(a[0]); r[1] = (short)f2bf(a[1]);
    r[2] = (short)f2bf(a[2]); r[3] = (short)f2bf(a[3]);
    r[4] = (short)f2bf(b[0]); r[5] = (short)f2bf(b[1]);
    r[6] = (short)f2bf(b[2]); r[7] = (short)f2bf(b[3]);
    return r;
}

// ---------------- k0: weight transposes (tiny) ----------------
// Wt[c][m]  = RW[m][f][k]  with c = k*128+f   (512 x 128 bf16)
// SWt[l][m] = SW[m][l]                        (128 x 128 bf16)
__global__ void k0_weights(const float* __restrict__ RW, const float* __restrict__ SW,
                           unsigned short* __restrict__ Wt, unsigned short* __restrict__ SWt) {
    int r = blockIdx.x;   // 0..639
    int m = threadIdx.x;  // 0..127
    if (r < 512) {
        int k = r >> 7, f = r & 127;
        Wt[r * F_ + m] = f2bf(RW[(m * F_ + f) * K_ + k]);
    } else {
        int l = r - 512;
        SWt[l * F_ + m] = f2bf(SW[m * F_ + l]);
    }
}

// ---------------- k1: colsum[b][j] = sum_{k,i} E[b,k,i,j] ----------------
__global__ void k1_colsum(const float* __restrict__ E, float* __restrict__ colsum) {
    int bid = blockIdx.x;           // 1024 blocks
    int b   = bid >> 5;             // 0..31
    int jt  = (bid >> 4) & 1;       // 0..1
    int isl = bid & 15;             // 0..15  (32 rows each)
    int j   = jt * 256 + threadIdx.x;
    int i0  = isl * 32;
    float s0 = 0.f, s1 = 0.f, s2 = 0.f, s3 = 0.f;
#pragma unroll
    for (int k = 0; k < K_; ++k) {
        const float* p = E + ((size_t)((b * K_ + k) * N_ + i0)) * N_ + j;
#pragma unroll 4
        for (int ii = 0; ii < 32; ii += 4) {
            s0 += p[(ii + 0) * N_];
            s1 += p[(ii + 1) * N_];
            s2 += p[(ii + 2) * N_];
            s3 += p[(ii + 3) * N_];
        }
    }
    atomicAdd(&colsum[b * N_ + j], (s0 + s1) + (s2 + s3));
}

// ---------------- k2: Tt[b][c][j] = sum_m Wt[c][m] * H[b][j][m]  (bf16 out) ----------------
// Transposed-orientation MFMA: rows = c (512), cols = j (512), K-dim = m (128).
__global__ void k2_expand(const float* __restrict__ H, const unsigned short* __restrict__ Wt,
                          unsigned short* __restrict__ Tt) {
    int bid = blockIdx.x;        // 1024 blocks
    int b  = bid >> 5;           // 0..31
    int ct = (bid >> 2) & 7;     // 0..7   (64 c-rows)
    int jt = bid & 3;            // 0..3   (128 j-cols)
    int lane = threadIdx.x & 63;
    int wv   = threadIdx.x >> 6; // 0..3
    int c0 = ct * 64 + wv * 16;
    int jbase = jt * 128;
    int lrow = lane & 15, lgrp = lane >> 4;

    float4v acc[8];
#pragma unroll
    for (int i = 0; i < 8; ++i) acc[i] = {0.f, 0.f, 0.f, 0.f};

#pragma unroll
    for (int ms = 0; ms < 4; ++ms) {
        int m0 = ms * 32;
        // A-frag: Wt[c0+lrow][m0 + lgrp*8 .. +8]  (contiguous 16B bf16)
        short8 a = *(const short8*)(Wt + (c0 + lrow) * F_ + m0 + lgrp * 8);
#pragma unroll
        for (int cf = 0; cf < 8; ++cf) {
            int j = jbase + cf * 16 + lrow;
            const float* hp = H + ((size_t)b * N_ + j) * F_ + m0 + lgrp * 8;
            float4v h0 = *(const float4v*)hp;
            float4v h1 = *(const float4v*)(hp + 4);
            short8 bb = pack8(h0, h1);
            acc[cf] = __builtin_amdgcn_mfma_f32_16x16x32_bf16(a, bb, acc[cf], 0, 0, 0);
        }
    }
#pragma unroll
    for (int cf = 0; cf < 8; ++cf) {
#pragma unroll
        for (int r = 0; r < 4; ++r) {
            int c = c0 + lgrp * 4 + r;
            int j = jbase + cf * 16 + lrow;
            Tt[((size_t)b * 512 + c) * N_ + j] = f2bf(acc[cf][r]);
        }
    }
}

// ---------------- k3: rel + self + fused epilogue ----------------
// out[b,i,f] = sigmoid( D[b,i] * sum_{k,j} E[b,k,i,j]*Tt[b][k*128+f][j]
//                       + sum_m H[b,i,m]*SWt[f][m] )
__global__ void __launch_bounds__(512)
k3_fuse(const float* __restrict__ E, const float* __restrict__ H,
        const unsigned short* __restrict__ Tt, const unsigned short* __restrict__ SWt,
        const float* __restrict__ colsum, float* __restrict__ out) {
    int bid = blockIdx.x;        // 256 blocks
    int b  = bid >> 3;           // 0..31
    int it = bid & 7;            // 0..7  (64 i-rows)
    int lane = threadIdx.x & 63;
    int wv   = threadIdx.x >> 6; // 0..7
    int i0 = it * 64 + (wv >> 1) * 16;
    int f0 = (wv & 1) * 64;
    int lrow = lane & 15, lgrp = lane >> 4;

    float4v accR[4], accS[4];
#pragma unroll
    for (int i = 0; i < 4; ++i) { accR[i] = {0.f, 0.f, 0.f, 0.f}; accS[i] = {0.f, 0.f, 0.f, 0.f}; }

    // phase 1: rel accumulation over k (4) and j (512 in steps of 32)
    for (int k = 0; k < K_; ++k) {
        const float* Eb = E + ((size_t)((b * K_ + k) * N_ + i0 + lrow)) * N_;
        const unsigned short* Tb = Tt + ((size_t)b * 512 + k * 128 + f0) * N_;
#pragma unroll 2
        for (int js = 0; js < 16; ++js) {
            int j0 = js * 32;
            const float* ep = Eb + j0 + lgrp * 8;
            float4v e0 = *(const float4v*)ep;
            float4v e1 = *(const float4v*)(ep + 4);
            short8 a = pack8(e0, e1);
#pragma unroll
            for (int cf = 0; cf < 4; ++cf) {
                const unsigned short* tp = Tb + (size_t)(cf * 16 + lrow) * N_ + j0 + lgrp * 8;
                short8 bb = *(const short8*)tp;
                accR[cf] = __builtin_amdgcn_mfma_f32_16x16x32_bf16(a, bb, accR[cf], 0, 0, 0);
            }
        }
    }

    // phase 2: self term, K-dim = m (128)
    {
        const float* Hp = H + ((size_t)b * N_ + i0 + lrow) * F_;
#pragma unroll
        for (int ms = 0; ms < 4; ++ms) {
            int m0 = ms * 32;
            const float* hp = Hp + m0 + lgrp * 8;
            float4v h0 = *(const float4v*)hp;
            float4v h1 = *(const float4v*)(hp + 4);
            short8 a = pack8(h0, h1);
#pragma unroll
            for (int cf = 0; cf < 4; ++cf) {
                const unsigned short* sp = SWt + (f0 + cf * 16 + lrow) * F_ + m0 + lgrp * 8;
                short8 bb = *(const short8*)sp;
                accS[cf] = __builtin_amdgcn_mfma_f32_16x16x32_bf16(a, bb, accS[cf], 0, 0, 0);
            }
        }
    }

    // epilogue: D scale + sigmoid
    float Dv[4];
#pragma unroll
    for (int r = 0; r < 4; ++r) {
        int i = i0 + lgrp * 4 + r;
        Dv[r] = 1.0f / (colsum[b * N_ + i] + (float)K_);
    }
#pragma unroll
    for (int cf = 0; cf < 4; ++cf) {
#pragma unroll
        for (int r = 0; r < 4; ++r) {
            int i = i0 + lgrp * 4 + r;
            int f = f0 + cf * 16 + lrow;
            float x = Dv[r] * accR[cf][r] + accS[cf][r];
            out[((size_t)b * N_ + i) * F_ + f] = 1.0f / (1.0f + __expf(-x));
        }
    }
}

extern "C" void kernel_launch(void* const* d_in, const int* in_sizes, int n_in,
                              void* d_out, int out_size, void* d_ws, size_t ws_size,
                              hipStream_t stream) {
    const float* H  = (const float*)d_in[0];
    const float* E  = (const float*)d_in[1];
    const float* RW = (const float*)d_in[2];
    const float* SW = (const float*)d_in[3];
    float* out = (float*)d_out;

    char* ws = (char*)d_ws;
    unsigned short* Wt  = (unsigned short*)(ws);             // 512*128*2  = 128 KiB
    unsigned short* SWt = (unsigned short*)(ws + 131072);    // 128*128*2  =  32 KiB
    float* colsum       = (float*)(ws + 163840);             // 32*512*4   =  64 KiB
    unsigned short* Tt  = (unsigned short*)(ws + 262144);    // 32*512*512*2 = 16 MiB

    hipMemsetAsync(colsum, 0, B_ * N_ * sizeof(float), stream);
    k0_weights<<<640, 128, 0, stream>>>(RW, SW, Wt, SWt);
    k1_colsum<<<1024, 256, 0, stream>>>(E, colsum);
    k2_expand<<<1024, 256, 0, stream>>>(H, Wt, Tt);
    k3_fuse<<<256, 512, 0, stream>>>(E, H, Tt, SWt, colsum, out);
}